// Round 1
// baseline (1613.921 us; speedup 1.0000x reference)
//
#include <hip/hip_runtime.h>
#include <hip/hip_bf16.h>

#define N_NODES 50000
#define N_EDGES 800000
#define IN_DIM  128
#define H_DIM   96
#define C_DIM   10
#define L_LAYERS 4
#define K_EIG   16
#define LN_EPS_F 1e-5f

// ---------- device helpers ----------

__device__ __forceinline__ float wave_sum64(float v) {
#pragma unroll
    for (int off = 32; off > 0; off >>= 1) v += __shfl_xor(v, off);
    return v;
}

__device__ __forceinline__ float gelu_f(float x) {
    return 0.5f * x * (1.0f + erff(x * 0.7071067811865476f));
}

// y = x @ W  where W (96x96) is in LDS, row layout: x0 = row[lane], x1 = row[64+lane] (lane<32)
__device__ __forceinline__ void gemv96_lds(const float* Wl, float x0, float x1,
                                           int j1, int j2, float& o0, float& o1) {
    float a0 = 0.f, a1 = 0.f;
#pragma unroll
    for (int k = 0; k < 64; ++k) {
        float xv = __shfl(x0, k);
        a0 = fmaf(xv, Wl[k * 96 + j1], a0);
        a1 = fmaf(xv, Wl[k * 96 + j2], a1);
    }
#pragma unroll
    for (int k = 0; k < 32; ++k) {
        float xv = __shfl(x1, k);
        a0 = fmaf(xv, Wl[(64 + k) * 96 + j1], a0);
        a1 = fmaf(xv, Wl[(64 + k) * 96 + j2], a1);
    }
    o0 = a0; o1 = a1;
}

// in-place LayerNorm over the 96 values held as (a0 on lanes 0..63, a1 on lanes 0..31)
__device__ __forceinline__ void ln96(float& a0, float& a1, int lane,
                                     float gj1, float gj2, float bj1, float bj2) {
    float a1m  = (lane < 32) ? a1 : 0.f;
    float mean = wave_sum64(a0 + a1m) * (1.f / 96.f);
    float d0 = a0 - mean, d1 = a1 - mean;
    float sq  = d0 * d0 + ((lane < 32) ? d1 * d1 : 0.f);
    float var = wave_sum64(sq) * (1.f / 96.f);
    float rs  = rsqrtf(var + LN_EPS_F);
    a0 = d0 * rs * gj1 + bj1;
    a1 = d1 * rs * gj2 + bj2;
}

// ---------- graph preprocessing ----------

__global__ void k_count(const int* __restrict__ dst, int* __restrict__ cnt) {
    int e = blockIdx.x * 256 + threadIdx.x;
    if (e < N_EDGES) atomicAdd(&cnt[dst[e]], 1);
}

__global__ void k_dinv(const int* __restrict__ cnt, float* __restrict__ dinv) {
    int n = blockIdx.x * 256 + threadIdx.x;
    if (n < N_NODES) dinv[n] = rsqrtf((float)cnt[n] + 1.0f);
}

// single-block exclusive scan of cnt[0..n) -> rowst[0..n], rowst[n] = total
__global__ void k_scan(const int* __restrict__ cnt, int* __restrict__ rowst, int n) {
    __shared__ int wsum[16];
    const int tid = threadIdx.x, lane = tid & 63, wid = tid >> 6;
    int carry = 0;
    for (int base = 0; base < n; base += 1024) {
        int i = base + tid;
        int v = (i < n) ? cnt[i] : 0;
        int s = v;
#pragma unroll
        for (int off = 1; off < 64; off <<= 1) {
            int t = __shfl_up(s, off);
            if (lane >= off) s += t;
        }
        if (lane == 63) wsum[wid] = s;
        __syncthreads();
        if (tid < 64) {
            int ws = (lane < 16) ? wsum[lane] : 0;
#pragma unroll
            for (int off = 1; off < 16; off <<= 1) {
                int t = __shfl_up(ws, off);
                if (lane >= off) ws += t;
            }
            if (lane < 16) wsum[lane] = ws;
        }
        __syncthreads();
        int woff = (wid > 0) ? wsum[wid - 1] : 0;
        if (i < n) rowst[i] = carry + woff + s - v;  // exclusive
        int tot = wsum[15];
        __syncthreads();  // protect wsum before next chunk overwrites
        carry += tot;
    }
    if (tid == 0) rowst[n] = carry;
}

__global__ void k_fill(const int* __restrict__ src, const int* __restrict__ dst,
                       const float* __restrict__ dinv, const int* __restrict__ rowst,
                       int* __restrict__ cursor, int* __restrict__ csr_s, float* __restrict__ csr_w) {
    int e = blockIdx.x * 256 + threadIdx.x;
    if (e >= N_EDGES) return;
    int s = src[e], d = dst[e];
    int p = atomicAdd(&cursor[d], 1);
    int slot = rowst[d] + p;
    csr_s[slot] = s;
    csr_w[slot] = dinv[s] * dinv[d];
}

// ---------- encoder: h = LN(x @ enc_W + enc_b; in_g, in_b) ----------

__launch_bounds__(256)
__global__ void k_encoder(const float* __restrict__ x, const float* __restrict__ W,
                          const float* __restrict__ b, const float* __restrict__ g,
                          const float* __restrict__ beta, float* __restrict__ h) {
    __shared__ float Wl[IN_DIM * 96];
    for (int i = threadIdx.x; i < IN_DIM * 96 / 4; i += 256)
        ((float4*)Wl)[i] = ((const float4*)W)[i];
    __syncthreads();
    const int lane = threadIdx.x & 63, wid = threadIdx.x >> 6;
    int j2 = 64 + lane; if (j2 >= 96) j2 -= 96;
    float bj1 = b[lane], bj2 = b[j2], gj1 = g[lane], gj2 = g[j2], nj1 = beta[lane], nj2 = beta[j2];
    int w = blockIdx.x * 4 + wid, stride = gridDim.x * 4;
    for (int row = w; row < N_NODES; row += stride) {
        const float* xr = x + (size_t)row * IN_DIM;
        float x0 = xr[lane], x1 = xr[64 + lane];
        float a0 = 0.f, a1 = 0.f;
#pragma unroll
        for (int k = 0; k < 64; ++k) {
            float xv = __shfl(x0, k);
            a0 = fmaf(xv, Wl[k * 96 + lane], a0);
            a1 = fmaf(xv, Wl[k * 96 + j2], a1);
        }
#pragma unroll
        for (int k = 0; k < 64; ++k) {
            float xv = __shfl(x1, k);
            a0 = fmaf(xv, Wl[(64 + k) * 96 + lane], a0);
            a1 = fmaf(xv, Wl[(64 + k) * 96 + j2], a1);
        }
        a0 += bj1; a1 += bj2;
        ln96(a0, a1, lane, gj1, gj2, nj1, nj2);
        h[(size_t)row * 96 + lane] = a0;
        if (lane < 32) h[(size_t)row * 96 + 64 + lane] = a1;
    }
}

// ---------- generic 96x96 GEMV stages ----------
// MODE 0: out = X @ W                      (conv xw)
// MODE 1: PE stage-1 then out = s @ W      (pe_a)
// MODE 2: out = relu(X @ W + bias)         (pe_b, in-place safe)
// MODE 3: out += X @ W + bias              (pe_c, residual into h)
// MODE 4: out = LN(gelu(X @ W + bias); g, beta)   (head stage-1)

template <int MODE>
__launch_bounds__(256)
__global__ void k_gemv96(const float* X, const float* __restrict__ W,
                         const float* __restrict__ bias, const float* __restrict__ g,
                         const float* __restrict__ beta, float* out,
                         const float* __restrict__ eigvecs, const float* __restrict__ eigvals,
                         const float* __restrict__ pe_eps, const float* __restrict__ phi_w1) {
    __shared__ float Wl[96 * 96];
    for (int i = threadIdx.x; i < 96 * 96 / 4; i += 256)
        ((float4*)Wl)[i] = ((const float4*)W)[i];
    __syncthreads();
    const int lane = threadIdx.x & 63, wid = threadIdx.x >> 6;
    int j2 = 64 + lane; if (j2 >= 96) j2 -= 96;
    float bj1 = 0.f, bj2 = 0.f, gj1 = 0.f, gj2 = 0.f, nj1 = 0.f, nj2 = 0.f;
    if (MODE == 2 || MODE == 3 || MODE == 4) { bj1 = bias[lane]; bj2 = bias[j2]; }
    if (MODE == 4) { gj1 = g[lane]; gj2 = g[j2]; nj1 = beta[lane]; nj2 = beta[j2]; }
    float w10j1 = 0.f, w11j1 = 0.f, w10j2 = 0.f, w11j2 = 0.f;
    if (MODE == 1) {
        w10j1 = phi_w1[lane]; w11j1 = phi_w1[96 + lane];
        w10j2 = phi_w1[j2];   w11j2 = phi_w1[96 + j2];
    }
    int w = blockIdx.x * 4 + wid, stride = gridDim.x * 4;
    for (int row = w; row < N_NODES; row += stride) {
        float x0, x1 = 0.f;
        if (MODE == 1) {
            // stage 1: s_j = sum_k relu(vec*phi_w1[0,j] + ev*phi_w1[1,j])
            float v0 = 0.f;
            if (lane < 16) v0 = eigvecs[(size_t)row * K_EIG + lane];
            else if (lane < 32) v0 = eigvals[(size_t)row * K_EIG + (lane - 16)] + pe_eps[lane - 16];
            float s0 = 0.f, s1 = 0.f;
#pragma unroll
            for (int k = 0; k < K_EIG; ++k) {
                float a = __shfl(v0, k);
                float b = __shfl(v0, 16 + k);
                float t0 = fmaf(a, w10j1, b * w11j1);
                float t1 = fmaf(a, w10j2, b * w11j2);
                s0 += fmaxf(t0, 0.f);
                s1 += fmaxf(t1, 0.f);
            }
            x0 = s0; x1 = s1;
        } else {
            const float* xr = X + (size_t)row * 96;
            x0 = xr[lane];
            if (lane < 32) x1 = xr[64 + lane];
        }
        float a0, a1;
        gemv96_lds(Wl, x0, x1, lane, j2, a0, a1);
        if (MODE == 2 || MODE == 3 || MODE == 4) { a0 += bj1; a1 += bj2; }
        if (MODE == 2) { a0 = fmaxf(a0, 0.f); a1 = fmaxf(a1, 0.f); }
        if (MODE == 4) {
            a0 = gelu_f(a0); a1 = gelu_f(a1);
            ln96(a0, a1, lane, gj1, gj2, nj1, nj2);
        }
        size_t o0i = (size_t)row * 96 + lane;
        size_t o1i = (size_t)row * 96 + 64 + lane;
        if (MODE == 3) {
            out[o0i] += a0;
            if (lane < 32) out[o1i] += a1;
        } else {
            out[o0i] = a0;
            if (lane < 32) out[o1i] = a1;
        }
    }
}

// ---------- GCN aggregation + bias + gelu + LN + residual ----------

__launch_bounds__(256)
__global__ void k_agg(const float* __restrict__ xw, const int* __restrict__ rowst,
                      const int* __restrict__ csr_s, const float* __restrict__ csr_w,
                      const float* __restrict__ dinv,
                      const float* __restrict__ bias, const float* __restrict__ g,
                      const float* __restrict__ beta, float* __restrict__ h) {
    const int lane = threadIdx.x & 63, wid = threadIdx.x >> 6;
    int j2 = 64 + lane; if (j2 >= 96) j2 -= 96;
    float bj1 = bias[lane], bj2 = bias[j2], gj1 = g[lane], gj2 = g[j2], nj1 = beta[lane], nj2 = beta[j2];
    int w = blockIdx.x * 4 + wid, stride = gridDim.x * 4;
    for (int row = w; row < N_NODES; row += stride) {
        int rs = rowst[row], re = rowst[row + 1];
        float dv = dinv[row];
        float d2 = dv * dv;
        const float* xr = xw + (size_t)row * 96;
        float a0 = xr[lane] * d2;
        float a1 = (lane < 32) ? xr[64 + lane] * d2 : 0.f;
        for (int i = rs; i < re; ++i) {
            int s = csr_s[i];
            float wt = csr_w[i];
            const float* xs = xw + (size_t)s * 96;
            a0 = fmaf(wt, xs[lane], a0);
            if (lane < 32) a1 = fmaf(wt, xs[64 + lane], a1);
        }
        a0 += bj1; a1 += bj2;
        a0 = gelu_f(a0); a1 = gelu_f(a1);
        ln96(a0, a1, lane, gj1, gj2, nj1, nj2);
        h[(size_t)row * 96 + lane] += a0;
        if (lane < 32) h[(size_t)row * 96 + 64 + lane] += a1;
    }
}

// ---------- head stage 2: out = Z @ head_w2 + head_b2  (96 -> 10) ----------

__launch_bounds__(256)
__global__ void k_headb(const float* __restrict__ Z, const float* __restrict__ W2,
                        const float* __restrict__ b2, float* __restrict__ out) {
    __shared__ float Wl[96 * C_DIM];
    for (int i = threadIdx.x; i < 96 * C_DIM; i += 256) Wl[i] = W2[i];
    __syncthreads();
    const int lane = threadIdx.x & 63, wid = threadIdx.x >> 6;
    float b2r[C_DIM];
#pragma unroll
    for (int j = 0; j < C_DIM; ++j) b2r[j] = b2[j];
    int w = blockIdx.x * 4 + wid, stride = gridDim.x * 4;
    for (int row = w; row < N_NODES; row += stride) {
        const float* zr = Z + (size_t)row * 96;
        float z0 = zr[lane];
        float z1 = (lane < 32) ? zr[64 + lane] : 0.f;
        float acc[C_DIM];
#pragma unroll
        for (int j = 0; j < C_DIM; ++j) {
            acc[j] = z0 * Wl[lane * C_DIM + j];
            if (lane < 32) acc[j] = fmaf(z1, Wl[(64 + lane) * C_DIM + j], acc[j]);
        }
#pragma unroll
        for (int j = 0; j < C_DIM; ++j) acc[j] = wave_sum64(acc[j]);
        if (lane == 0) {
#pragma unroll
            for (int j = 0; j < C_DIM; ++j) out[(size_t)row * C_DIM + j] = acc[j] + b2r[j];
        }
    }
}

// ---------- host ----------

extern "C" void kernel_launch(void* const* d_in, const int* in_sizes, int n_in,
                              void* d_out, int out_size, void* d_ws, size_t ws_size,
                              hipStream_t stream) {
    (void)in_sizes; (void)n_in; (void)out_size; (void)ws_size;
    const float* x       = (const float*)d_in[0];
    const int*   eidx    = (const int*)d_in[1];
    const float* eigvecs = (const float*)d_in[2];
    const float* eigvals = (const float*)d_in[3];
    const float* enc_W   = (const float*)d_in[4];
    const float* enc_b   = (const float*)d_in[5];
    const float* in_g    = (const float*)d_in[6];
    const float* in_b    = (const float*)d_in[7];
    const float* phi_w1  = (const float*)d_in[8];
    const float* phi_w2  = (const float*)d_in[9];
    const float* rho_w1  = (const float*)d_in[10];
    const float* rho_b1  = (const float*)d_in[11];
    const float* rho_w2  = (const float*)d_in[12];
    const float* rho_b2  = (const float*)d_in[13];
    const float* pe_eps  = (const float*)d_in[14];
    const float* conv_W  = (const float*)d_in[15];
    const float* conv_b  = (const float*)d_in[16];
    const float* norm_g  = (const float*)d_in[17];
    const float* norm_b  = (const float*)d_in[18];
    const float* head_w1 = (const float*)d_in[19];
    const float* head_b1 = (const float*)d_in[20];
    const float* head_g  = (const float*)d_in[21];
    const float* head_b  = (const float*)d_in[22];
    const float* head_w2 = (const float*)d_in[23];
    const float* head_b2 = (const float*)d_in[24];
    float* out = (float*)d_out;

    const int* src = eidx;
    const int* dst = eidx + N_EDGES;

    char* ws = (char*)d_ws;
    size_t off = 0;
    auto alloc = [&](size_t bytes) {
        void* p = ws + off;
        off += (bytes + 255) & ~(size_t)255;
        return p;
    };
    float* h      = (float*)alloc(sizeof(float) * (size_t)N_NODES * H_DIM);
    float* xw     = (float*)alloc(sizeof(float) * (size_t)N_NODES * H_DIM);
    int*   cnt    = (int*)alloc(sizeof(int) * (N_NODES + 1));
    int*   cursor = (int*)alloc(sizeof(int) * N_NODES);
    int*   rowst  = (int*)alloc(sizeof(int) * (N_NODES + 1));
    float* dinv   = (float*)alloc(sizeof(float) * N_NODES);
    int*   csr_s  = (int*)alloc(sizeof(int) * N_EDGES);
    float* csr_w  = (float*)alloc(sizeof(float) * N_EDGES);

    // zero cnt + cursor (contiguous region)
    hipMemsetAsync(cnt, 0, (size_t)((char*)rowst - (char*)cnt), stream);

    const int eb = (N_EDGES + 255) / 256;
    const int nb = (N_NODES + 255) / 256;

    k_count<<<eb, 256, 0, stream>>>(dst, cnt);
    k_dinv<<<nb, 256, 0, stream>>>(cnt, dinv);
    k_scan<<<1, 1024, 0, stream>>>(cnt, rowst, N_NODES);
    k_fill<<<eb, 256, 0, stream>>>(src, dst, dinv, rowst, cursor, csr_s, csr_w);

    k_encoder<<<1024, 256, 0, stream>>>(x, enc_W, enc_b, in_g, in_b, h);

    // PE: t = (sum_k relu(z@phi_w1)) @ phi_w2 ; u = relu(t@rho_w1+b1); h += u@rho_w2+b2
    k_gemv96<1><<<1024, 256, 0, stream>>>(nullptr, phi_w2, nullptr, nullptr, nullptr, xw,
                                          eigvecs, eigvals, pe_eps, phi_w1);
    k_gemv96<2><<<1024, 256, 0, stream>>>(xw, rho_w1, rho_b1, nullptr, nullptr, xw,
                                          nullptr, nullptr, nullptr, nullptr);
    k_gemv96<3><<<1024, 256, 0, stream>>>(xw, rho_w2, rho_b2, nullptr, nullptr, h,
                                          nullptr, nullptr, nullptr, nullptr);

    for (int l = 0; l < L_LAYERS; ++l) {
        k_gemv96<0><<<1024, 256, 0, stream>>>(h, conv_W + (size_t)l * 96 * 96, nullptr, nullptr,
                                              nullptr, xw, nullptr, nullptr, nullptr, nullptr);
        k_agg<<<2048, 256, 0, stream>>>(xw, rowst, csr_s, csr_w, dinv,
                                        conv_b + (size_t)l * 96, norm_g + (size_t)l * 96,
                                        norm_b + (size_t)l * 96, h);
    }

    // head
    k_gemv96<4><<<1024, 256, 0, stream>>>(h, head_w1, head_b1, head_g, head_b, xw,
                                          nullptr, nullptr, nullptr, nullptr);
    k_headb<<<1024, 256, 0, stream>>>(xw, head_w2, head_b2, out);
}

// Round 2
// 882.630 us; speedup vs baseline: 1.8285x; 1.8285x over previous
//
#include <hip/hip_runtime.h>
#include <hip/hip_bf16.h>

#define N_NODES 50000
#define N_EDGES 800000
#define IN_DIM  128
#define H_DIM   96
#define C_DIM   10
#define L_LAYERS 4
#define K_EIG   16
#define LN_EPS_F 1e-5f

typedef __attribute__((ext_vector_type(8))) short bf16x8;
typedef __attribute__((ext_vector_type(4))) float f32x4;

// ---------- device helpers ----------

__device__ __forceinline__ float wave_sum64(float v) {
#pragma unroll
    for (int off = 32; off > 0; off >>= 1) v += __shfl_xor(v, off);
    return v;
}

__device__ __forceinline__ float gelu_f(float x) {
    return 0.5f * x * (1.0f + erff(x * 0.7071067811865476f));
}

__device__ __forceinline__ ushort f2bf(float f) {
    union { float f; unsigned int u; } v; v.f = f;
    unsigned int r = v.u + 0x7fffu + ((v.u >> 16) & 1u);
    return (ushort)(r >> 16);
}

__device__ __forceinline__ float bflo(unsigned int v) { return __uint_as_float(v << 16); }
__device__ __forceinline__ float bfhi(unsigned int v) { return __uint_as_float(v & 0xffff0000u); }

// ---------- graph preprocessing ----------

__global__ void k_count(const int* __restrict__ dst, int* __restrict__ cnt) {
    int e = blockIdx.x * 256 + threadIdx.x;
    if (e < N_EDGES) atomicAdd(&cnt[dst[e]], 1);
}

__global__ void k_dinv(const int* __restrict__ cnt, float* __restrict__ dinv) {
    int n = blockIdx.x * 256 + threadIdx.x;
    if (n < N_NODES) dinv[n] = rsqrtf((float)cnt[n] + 1.0f);
}

__global__ void k_scan(const int* __restrict__ cnt, int* __restrict__ rowst, int n) {
    __shared__ int wsum[16];
    const int tid = threadIdx.x, lane = tid & 63, wid = tid >> 6;
    int carry = 0;
    for (int base = 0; base < n; base += 1024) {
        int i = base + tid;
        int v = (i < n) ? cnt[i] : 0;
        int s = v;
#pragma unroll
        for (int off = 1; off < 64; off <<= 1) {
            int t = __shfl_up(s, off);
            if (lane >= off) s += t;
        }
        if (lane == 63) wsum[wid] = s;
        __syncthreads();
        if (tid < 64) {
            int ws = (lane < 16) ? wsum[lane] : 0;
#pragma unroll
            for (int off = 1; off < 16; off <<= 1) {
                int t = __shfl_up(ws, off);
                if (lane >= off) ws += t;
            }
            if (lane < 16) wsum[lane] = ws;
        }
        __syncthreads();
        int woff = (wid > 0) ? wsum[wid - 1] : 0;
        if (i < n) rowst[i] = carry + woff + s - v;
        int tot = wsum[15];
        __syncthreads();
        carry += tot;
    }
    if (tid == 0) rowst[n] = carry;
}

__global__ void k_fill(const int* __restrict__ src, const int* __restrict__ dst,
                       const float* __restrict__ dinv, const int* __restrict__ rowst,
                       int* __restrict__ cursor, int2* __restrict__ csr) {
    int e = blockIdx.x * 256 + threadIdx.x;
    if (e >= N_EDGES) return;
    int s = src[e], d = dst[e];
    int p = atomicAdd(&cursor[d], 1);
    csr[rowst[d] + p] = make_int2(s, __float_as_int(dinv[s] * dinv[d]));
}

// ---------- MFMA GEMM: out[M,96] = epi(X[M,K] @ W[K,96]) ----------
// EPI 0: -> bf16 out                 (conv xw, pe stage a)
// EPI 1: relu(.+bias) -> bf16        (pe stage b)
// EPI 2: LN(.+bias; g,beta) -> f32   (encoder)
// EPI 3: f32 out += . + bias         (pe residual)
// EPI 4: LN(gelu(.+bias); g,beta) -> f32  (head stage 1)

template <int K_DIM, typename XT, int EPI>
__launch_bounds__(256)
__global__ void k_gemm(const XT* __restrict__ X, const float* __restrict__ W,
                       const float* __restrict__ bias, const float* __restrict__ g,
                       const float* __restrict__ beta, void* __restrict__ outv) {
    constexpr int KP = K_DIM + 8;
    __shared__ ushort Xl[64 * KP];
    __shared__ ushort Wl[96 * KP];
    const int t = threadIdx.x;
    const int base = blockIdx.x * 64;

    // stage W transposed to bf16: Wl[n][k] = bf16(W[k][n])
    for (int i = t; i < K_DIM * 96; i += 256) {
        int k = i / 96, n = i - k * 96;
        Wl[n * KP + k] = f2bf(W[i]);
    }
    // stage X rows to bf16 (zero-pad invalid rows)
    constexpr int CH = 64 * K_DIM / 8;
    for (int i = t; i < CH; i += 256) {
        int r = (i * 8) / K_DIM, k = (i * 8) - r * K_DIM;
        int row = base + r;
        uint4 pk;
        if (row < N_NODES) {
            if (sizeof(XT) == 4) {
                const float4* p = (const float4*)((const float*)X + (size_t)row * K_DIM + k);
                float4 a = p[0], b = p[1];
                pk.x = (unsigned)f2bf(a.x) | ((unsigned)f2bf(a.y) << 16);
                pk.y = (unsigned)f2bf(a.z) | ((unsigned)f2bf(a.w) << 16);
                pk.z = (unsigned)f2bf(b.x) | ((unsigned)f2bf(b.y) << 16);
                pk.w = (unsigned)f2bf(b.z) | ((unsigned)f2bf(b.w) << 16);
            } else {
                pk = *(const uint4*)((const ushort*)X + (size_t)row * K_DIM + k);
            }
        } else { pk.x = pk.y = pk.z = pk.w = 0u; }
        *(uint4*)(&Xl[r * KP + k]) = pk;
    }
    __syncthreads();

    const int lane = t & 63, w = t >> 6;
    const int lrow = lane & 15, lk = (lane >> 4) * 8;

    bf16x8 af[K_DIM / 32];
#pragma unroll
    for (int kk = 0; kk < K_DIM / 32; ++kk)
        af[kk] = *(const bf16x8*)(&Xl[(w * 16 + lrow) * KP + kk * 32 + lk]);

    f32x4 acc[6];
#pragma unroll
    for (int nn = 0; nn < 6; ++nn) { acc[nn][0] = 0.f; acc[nn][1] = 0.f; acc[nn][2] = 0.f; acc[nn][3] = 0.f; }
#pragma unroll
    for (int nn = 0; nn < 6; ++nn) {
#pragma unroll
        for (int kk = 0; kk < K_DIM / 32; ++kk) {
            bf16x8 bf = *(const bf16x8*)(&Wl[(nn * 16 + lrow) * KP + kk * 32 + lk]);
            acc[nn] = __builtin_amdgcn_mfma_f32_16x16x32_bf16(af[kk], bf, acc[nn], 0, 0, 0);
        }
    }

    float bcol[6], gcol[6], ncol[6];
    if (EPI >= 1) {
#pragma unroll
        for (int nn = 0; nn < 6; ++nn) bcol[nn] = bias[nn * 16 + lrow];
    }
    if (EPI == 2 || EPI == 4) {
#pragma unroll
        for (int nn = 0; nn < 6; ++nn) { gcol[nn] = g[nn * 16 + lrow]; ncol[nn] = beta[nn * 16 + lrow]; }
    }

    const int rbase = base + w * 16 + (lane >> 4) * 4;
#pragma unroll
    for (int reg = 0; reg < 4; ++reg) {
        int row = rbase + reg;
        float v[6];
#pragma unroll
        for (int nn = 0; nn < 6; ++nn) {
            v[nn] = acc[nn][reg];
            if (EPI >= 1) v[nn] += bcol[nn];
            if (EPI == 1) v[nn] = fmaxf(v[nn], 0.f);
            if (EPI == 4) v[nn] = gelu_f(v[nn]);
        }
        if (EPI == 2 || EPI == 4) {
            float s = 0.f, s2 = 0.f;
#pragma unroll
            for (int nn = 0; nn < 6; ++nn) { s += v[nn]; s2 += v[nn] * v[nn]; }
#pragma unroll
            for (int off = 1; off < 16; off <<= 1) { s += __shfl_xor(s, off); s2 += __shfl_xor(s2, off); }
            float mean = s * (1.f / 96.f);
            float var = s2 * (1.f / 96.f) - mean * mean;
            float rs = rsqrtf(var + LN_EPS_F);
#pragma unroll
            for (int nn = 0; nn < 6; ++nn) v[nn] = (v[nn] - mean) * rs * gcol[nn] + ncol[nn];
        }
        if (row < N_NODES) {
#pragma unroll
            for (int nn = 0; nn < 6; ++nn) {
                size_t idx = (size_t)row * 96 + nn * 16 + lrow;
                if (EPI == 0 || EPI == 1) ((ushort*)outv)[idx] = f2bf(v[nn]);
                else if (EPI == 3) ((float*)outv)[idx] += v[nn];
                else ((float*)outv)[idx] = v[nn];
            }
        }
    }
}

// ---------- PE stage 1: s[n,96] = sum_k relu(z @ phi_w1) ----------

__launch_bounds__(256)
__global__ void k_pe1(const float* __restrict__ eigvecs, const float* __restrict__ eigvals,
                      const float* __restrict__ pe_eps, const float* __restrict__ phi_w1,
                      ushort* __restrict__ sout) {
    const int lane = threadIdx.x & 63, wid = threadIdx.x >> 6;
    const int j2 = 64 + (lane & 31);
    float w10 = phi_w1[lane], w11 = phi_w1[96 + lane];
    float w20 = phi_w1[j2],   w21 = phi_w1[96 + j2];
    int w = blockIdx.x * 4 + wid, stride = gridDim.x * 4;
    for (int row = w; row < N_NODES; row += stride) {
        float s1 = 0.f, s2 = 0.f;
#pragma unroll
        for (int k = 0; k < K_EIG; ++k) {
            float a = eigvecs[(size_t)row * K_EIG + k];
            float b = eigvals[(size_t)row * K_EIG + k] + pe_eps[k];
            s1 += fmaxf(fmaf(a, w10, b * w11), 0.f);
            s2 += fmaxf(fmaf(a, w20, b * w21), 0.f);
        }
        sout[(size_t)row * 96 + lane] = f2bf(s1);
        if (lane < 32) sout[(size_t)row * 96 + j2] = f2bf(s2);
    }
}

// ---------- GCN aggregation (bf16 gather) + bias + gelu + LN + residual ----------

__launch_bounds__(256)
__global__ void k_agg(const unsigned int* __restrict__ xw32, const int* __restrict__ rowst,
                      const int2* __restrict__ csr, const float* __restrict__ dinv,
                      const float* __restrict__ bias, const float* __restrict__ g,
                      const float* __restrict__ beta, float* __restrict__ h) {
    const int lane = threadIdx.x & 63, wid = threadIdx.x >> 6;
    const bool act = lane < 48;
    const int c0 = lane * 2;
    float b0 = 0.f, b1 = 0.f, g0 = 0.f, g1 = 0.f, n0 = 0.f, n1 = 0.f;
    if (act) { b0 = bias[c0]; b1 = bias[c0 + 1]; g0 = g[c0]; g1 = g[c0 + 1]; n0 = beta[c0]; n1 = beta[c0 + 1]; }
    int w = blockIdx.x * 4 + wid, stride = gridDim.x * 4;
    for (int row = w; row < N_NODES; row += stride) {
        int rs = rowst[row], re = rowst[row + 1];
        float dv = dinv[row], d2 = dv * dv;
        float a0 = 0.f, a1 = 0.f;
        if (act) {
            unsigned int v = xw32[row * 48 + lane];
            a0 = bflo(v) * d2; a1 = bfhi(v) * d2;
        }
        for (int i = rs; i < re; ++i) {
            int2 e = csr[i];
            float wt = __int_as_float(e.y);
            if (act) {
                unsigned int v = xw32[e.x * 48 + lane];
                a0 = fmaf(wt, bflo(v), a0);
                a1 = fmaf(wt, bfhi(v), a1);
            }
        }
        a0 += b0; a1 += b1;
        a0 = gelu_f(a0); a1 = gelu_f(a1);
        float mean = wave_sum64(a0 + a1) * (1.f / 96.f);
        float d0 = a0 - mean, d1 = a1 - mean;
        float sq = act ? (d0 * d0 + d1 * d1) : 0.f;
        float var = wave_sum64(sq) * (1.f / 96.f);
        float rs_ = rsqrtf(var + LN_EPS_F);
        if (act) {
            size_t ix = (size_t)row * 96 + c0;
            h[ix]     += d0 * rs_ * g0 + n0;
            h[ix + 1] += d1 * rs_ * g1 + n1;
        }
    }
}

// ---------- head stage 2: out = Z @ head_w2 + head_b2  (96 -> 10) ----------

__launch_bounds__(256)
__global__ void k_headb(const float* __restrict__ Z, const float* __restrict__ W2,
                        const float* __restrict__ b2, float* __restrict__ out) {
    __shared__ float Wl[96 * C_DIM];
    for (int i = threadIdx.x; i < 96 * C_DIM; i += 256) Wl[i] = W2[i];
    __syncthreads();
    const int lane = threadIdx.x & 63, wid = threadIdx.x >> 6;
    float b2r[C_DIM];
#pragma unroll
    for (int j = 0; j < C_DIM; ++j) b2r[j] = b2[j];
    int w = blockIdx.x * 4 + wid, stride = gridDim.x * 4;
    for (int row = w; row < N_NODES; row += stride) {
        const float* zr = Z + (size_t)row * 96;
        float z0 = zr[lane];
        float z1 = (lane < 32) ? zr[64 + lane] : 0.f;
        float acc[C_DIM];
#pragma unroll
        for (int j = 0; j < C_DIM; ++j) {
            acc[j] = z0 * Wl[lane * C_DIM + j];
            if (lane < 32) acc[j] = fmaf(z1, Wl[(64 + lane) * C_DIM + j], acc[j]);
        }
#pragma unroll
        for (int j = 0; j < C_DIM; ++j) acc[j] = wave_sum64(acc[j]);
        if (lane == 0) {
#pragma unroll
            for (int j = 0; j < C_DIM; ++j) out[(size_t)row * C_DIM + j] = acc[j] + b2r[j];
        }
    }
}

// ---------- host ----------

extern "C" void kernel_launch(void* const* d_in, const int* in_sizes, int n_in,
                              void* d_out, int out_size, void* d_ws, size_t ws_size,
                              hipStream_t stream) {
    (void)in_sizes; (void)n_in; (void)out_size; (void)ws_size;
    const float* x       = (const float*)d_in[0];
    const int*   eidx    = (const int*)d_in[1];
    const float* eigvecs = (const float*)d_in[2];
    const float* eigvals = (const float*)d_in[3];
    const float* enc_W   = (const float*)d_in[4];
    const float* enc_b   = (const float*)d_in[5];
    const float* in_g    = (const float*)d_in[6];
    const float* in_b    = (const float*)d_in[7];
    const float* phi_w1  = (const float*)d_in[8];
    const float* phi_w2  = (const float*)d_in[9];
    const float* rho_w1  = (const float*)d_in[10];
    const float* rho_b1  = (const float*)d_in[11];
    const float* rho_w2  = (const float*)d_in[12];
    const float* rho_b2  = (const float*)d_in[13];
    const float* pe_eps  = (const float*)d_in[14];
    const float* conv_W  = (const float*)d_in[15];
    const float* conv_b  = (const float*)d_in[16];
    const float* norm_g  = (const float*)d_in[17];
    const float* norm_b  = (const float*)d_in[18];
    const float* head_w1 = (const float*)d_in[19];
    const float* head_b1 = (const float*)d_in[20];
    const float* head_g  = (const float*)d_in[21];
    const float* head_b  = (const float*)d_in[22];
    const float* head_w2 = (const float*)d_in[23];
    const float* head_b2 = (const float*)d_in[24];
    float* out = (float*)d_out;

    const int* src = eidx;
    const int* dst = eidx + N_EDGES;

    char* ws = (char*)d_ws;
    size_t off = 0;
    auto alloc = [&](size_t bytes) {
        void* p = ws + off;
        off += (bytes + 255) & ~(size_t)255;
        return p;
    };
    float*  h     = (float*)alloc(sizeof(float) * (size_t)N_NODES * H_DIM);
    ushort* bufA  = (ushort*)alloc(sizeof(ushort) * (size_t)N_NODES * H_DIM);  // 9.6MB, 256-mult
    ushort* bufB  = (ushort*)alloc(sizeof(ushort) * (size_t)N_NODES * H_DIM);  // contiguous after bufA
    float*  zf    = (float*)bufA;  // aliases bufA+bufB (19.2MB), used after convs
    int*    cnt    = (int*)alloc(sizeof(int) * (N_NODES + 1));
    int*    cursor = (int*)alloc(sizeof(int) * N_NODES);
    int*    rowst  = (int*)alloc(sizeof(int) * (N_NODES + 1));
    float*  dinv   = (float*)alloc(sizeof(float) * N_NODES);
    int2*   csr    = (int2*)alloc(sizeof(int2) * N_EDGES);

    hipMemsetAsync(cnt, 0, (size_t)((char*)rowst - (char*)cnt), stream);

    const int eb = (N_EDGES + 255) / 256;
    const int nb = (N_NODES + 255) / 256;
    const int gb = (N_NODES + 63) / 64;  // GEMM row-tile blocks

    k_count<<<eb, 256, 0, stream>>>(dst, cnt);
    k_dinv<<<nb, 256, 0, stream>>>(cnt, dinv);
    k_scan<<<1, 1024, 0, stream>>>(cnt, rowst, N_NODES);
    k_fill<<<eb, 256, 0, stream>>>(src, dst, dinv, rowst, cursor, csr);

    // encoder: h = LN(x @ enc_W + enc_b)
    k_gemm<IN_DIM, float, 2><<<gb, 256, 0, stream>>>(x, enc_W, enc_b, in_g, in_b, h);

    // PE chain
    k_pe1<<<512, 256, 0, stream>>>(eigvecs, eigvals, pe_eps, phi_w1, bufA);
    k_gemm<96, ushort, 0><<<gb, 256, 0, stream>>>(bufA, phi_w2, nullptr, nullptr, nullptr, bufB);
    k_gemm<96, ushort, 1><<<gb, 256, 0, stream>>>(bufB, rho_w1, rho_b1, nullptr, nullptr, bufA);
    k_gemm<96, ushort, 3><<<gb, 256, 0, stream>>>(bufA, rho_w2, rho_b2, nullptr, nullptr, h);

    // GCN layers
    for (int l = 0; l < L_LAYERS; ++l) {
        k_gemm<96, float, 0><<<gb, 256, 0, stream>>>(h, conv_W + (size_t)l * 96 * 96,
                                                     nullptr, nullptr, nullptr, bufA);
        k_agg<<<1024, 256, 0, stream>>>((const unsigned int*)bufA, rowst, csr, dinv,
                                        conv_b + (size_t)l * 96, norm_g + (size_t)l * 96,
                                        norm_b + (size_t)l * 96, h);
    }

    // head
    k_gemm<96, float, 4><<<gb, 256, 0, stream>>>(h, head_w1, head_b1, head_g, head_b, zf);
    k_headb<<<512, 256, 0, stream>>>(zf, head_w2, head_b2, out);
}

// Round 3
// 382.986 us; speedup vs baseline: 4.2140x; 2.3046x over previous
//
#include <hip/hip_runtime.h>
#include <hip/hip_bf16.h>

#define N_NODES 50000
#define N_EDGES 800000
#define IN_DIM  128
#define H_DIM   96
#define C_DIM   10
#define L_LAYERS 4
#define K_EIG   16
#define LN_EPS_F 1e-5f

typedef __attribute__((ext_vector_type(8))) short bf16x8;
typedef __attribute__((ext_vector_type(4))) float f32x4;

// ---------- device helpers ----------

__device__ __forceinline__ float wave_sum64(float v) {
#pragma unroll
    for (int off = 32; off > 0; off >>= 1) v += __shfl_xor(v, off);
    return v;
}

__device__ __forceinline__ float gelu_f(float x) {
    return 0.5f * x * (1.0f + erff(x * 0.7071067811865476f));
}

__device__ __forceinline__ ushort f2bf(float f) {
    union { float f; unsigned int u; } v; v.f = f;
    unsigned int r = v.u + 0x7fffu + ((v.u >> 16) & 1u);
    return (ushort)(r >> 16);
}

__device__ __forceinline__ float bflo(unsigned int v) { return __uint_as_float(v << 16); }
__device__ __forceinline__ float bfhi(unsigned int v) { return __uint_as_float(v & 0xffff0000u); }

// ---------- graph preprocessing ----------

__global__ void k_count(const int* __restrict__ dst, int* __restrict__ cnt) {
    int e = blockIdx.x * 256 + threadIdx.x;
    if (e < N_EDGES) atomicAdd(&cnt[dst[e]], 1);
}

__global__ void k_dinv(const int* __restrict__ cnt, float* __restrict__ dinv) {
    int n = blockIdx.x * 256 + threadIdx.x;
    if (n < N_NODES) dinv[n] = rsqrtf((float)cnt[n] + 1.0f);
}

// 3-phase exclusive scan of cnt[0..n) -> rowst[0..n]
__global__ void k_scanA(const int* __restrict__ cnt, int* __restrict__ rowst,
                        int* __restrict__ btot, int n) {
    __shared__ int wsum[16];
    const int tid = threadIdx.x, lane = tid & 63, wid = tid >> 6;
    int i = blockIdx.x * 1024 + tid;
    int v = (i < n) ? cnt[i] : 0;
    int s = v;
#pragma unroll
    for (int off = 1; off < 64; off <<= 1) {
        int t = __shfl_up(s, off);
        if (lane >= off) s += t;
    }
    if (lane == 63) wsum[wid] = s;
    __syncthreads();
    if (tid < 64) {
        int ws = (lane < 16) ? wsum[lane] : 0;
#pragma unroll
        for (int off = 1; off < 16; off <<= 1) {
            int t = __shfl_up(ws, off);
            if (lane >= off) ws += t;
        }
        if (lane < 16) wsum[lane] = ws;
    }
    __syncthreads();
    int woff = (wid > 0) ? wsum[wid - 1] : 0;
    if (i < n) rowst[i] = woff + s - v;  // block-local exclusive
    if (tid == 0) btot[blockIdx.x] = wsum[15];
}

__global__ void k_scanB(int* __restrict__ btot, int* __restrict__ bpre,
                        int* __restrict__ rowst, int n, int nblk) {
    int lane = threadIdx.x;
    int v = (lane < nblk) ? btot[lane] : 0;
    int s = v;
#pragma unroll
    for (int off = 1; off < 64; off <<= 1) {
        int t = __shfl_up(s, off);
        if (lane >= off) s += t;
    }
    if (lane < nblk) bpre[lane] = s - v;
    if (lane == 63) rowst[n] = s;
}

__global__ void k_scanC(int* __restrict__ rowst, const int* __restrict__ bpre, int n) {
    int i = blockIdx.x * 1024 + threadIdx.x;
    if (i < n) rowst[i] += bpre[blockIdx.x];
}

__global__ void k_fill(const int* __restrict__ src, const int* __restrict__ dst,
                       const float* __restrict__ dinv, const int* __restrict__ rowst,
                       int* __restrict__ cursor, int2* __restrict__ csr) {
    int e = blockIdx.x * 256 + threadIdx.x;
    if (e >= N_EDGES) return;
    int s = src[e], d = dst[e];
    int p = atomicAdd(&cursor[d], 1);
    csr[rowst[d] + p] = make_int2(s, __float_as_int(dinv[s] * dinv[d]));
}

// ---------- weight prep: transpose + bf16 ----------
// layout: [0,12288): enc_W (K=128, [n][k]); then 8 mats of 9216 (K=96):
// phi_w2, rho_w1, rho_w2, conv0..3, head_w1

struct WSrc { const float* p[9]; };

__global__ void k_prep(WSrc ws, ushort* __restrict__ out) {
    int idx = blockIdx.x * 256 + threadIdx.x;
    if (idx < 12288) {
        int n = idx >> 7, k = idx & 127;
        out[idx] = f2bf(ws.p[0][k * 96 + n]);
    } else if (idx < 12288 + 8 * 9216) {
        int j = idx - 12288;
        int m = j / 9216, r = j - m * 9216;
        int n = r / 96, k = r - n * 96;
        out[idx] = f2bf(ws.p[m + 1][k * 96 + n]);
    }
}

// ---------- MFMA GEMM: out[M,96] = epi(X[M,K] @ W[K,96]) ----------
// Wt: pre-transposed bf16 [96][K]
// EPI 0: -> bf16 out
// EPI 1: relu(.+bias) -> bf16
// EPI 2: LN(.+bias; g,beta) -> f32
// EPI 3: f32 out += . + bias
// EPI 4: LN(gelu(.+bias); g,beta) -> f32

template <int K_DIM, typename XT, int EPI>
__launch_bounds__(256)
__global__ void k_gemm(const XT* __restrict__ X, const ushort* __restrict__ Wt,
                       const float* __restrict__ bias, const float* __restrict__ g,
                       const float* __restrict__ beta, void* __restrict__ outv) {
    constexpr int KP = K_DIM + 8;
    __shared__ ushort Xl[64 * KP];
    __shared__ ushort Wl[96 * KP];
    const int t = threadIdx.x;
    const int base = blockIdx.x * 64;

    for (int i = t; i < 96 * (K_DIM / 8); i += 256) {
        int n = i / (K_DIM / 8), kc = (i - n * (K_DIM / 8)) * 8;
        *(uint4*)(&Wl[n * KP + kc]) = *(const uint4*)(&Wt[n * K_DIM + kc]);
    }
    constexpr int CH = 64 * K_DIM / 8;
    for (int i = t; i < CH; i += 256) {
        int r = (i * 8) / K_DIM, k = (i * 8) - r * K_DIM;
        int row = base + r;
        uint4 pk;
        if (row < N_NODES) {
            if (sizeof(XT) == 4) {
                const float4* p = (const float4*)((const float*)X + (size_t)row * K_DIM + k);
                float4 a = p[0], b = p[1];
                pk.x = (unsigned)f2bf(a.x) | ((unsigned)f2bf(a.y) << 16);
                pk.y = (unsigned)f2bf(a.z) | ((unsigned)f2bf(a.w) << 16);
                pk.z = (unsigned)f2bf(b.x) | ((unsigned)f2bf(b.y) << 16);
                pk.w = (unsigned)f2bf(b.z) | ((unsigned)f2bf(b.w) << 16);
            } else {
                pk = *(const uint4*)((const ushort*)X + (size_t)row * K_DIM + k);
            }
        } else { pk.x = pk.y = pk.z = pk.w = 0u; }
        *(uint4*)(&Xl[r * KP + k]) = pk;
    }
    __syncthreads();

    const int lane = t & 63, w = t >> 6;
    const int lrow = lane & 15, lk = (lane >> 4) * 8;

    bf16x8 af[K_DIM / 32];
#pragma unroll
    for (int kk = 0; kk < K_DIM / 32; ++kk)
        af[kk] = *(const bf16x8*)(&Xl[(w * 16 + lrow) * KP + kk * 32 + lk]);

    f32x4 acc[6];
#pragma unroll
    for (int nn = 0; nn < 6; ++nn) { acc[nn][0] = 0.f; acc[nn][1] = 0.f; acc[nn][2] = 0.f; acc[nn][3] = 0.f; }
#pragma unroll
    for (int nn = 0; nn < 6; ++nn) {
#pragma unroll
        for (int kk = 0; kk < K_DIM / 32; ++kk) {
            bf16x8 bf = *(const bf16x8*)(&Wl[(nn * 16 + lrow) * KP + kk * 32 + lk]);
            acc[nn] = __builtin_amdgcn_mfma_f32_16x16x32_bf16(af[kk], bf, acc[nn], 0, 0, 0);
        }
    }

    float bcol[6], gcol[6], ncol[6];
    if (EPI >= 1) {
#pragma unroll
        for (int nn = 0; nn < 6; ++nn) bcol[nn] = bias[nn * 16 + lrow];
    }
    if (EPI == 2 || EPI == 4) {
#pragma unroll
        for (int nn = 0; nn < 6; ++nn) { gcol[nn] = g[nn * 16 + lrow]; ncol[nn] = beta[nn * 16 + lrow]; }
    }

    const int rbase = base + w * 16 + (lane >> 4) * 4;
#pragma unroll
    for (int reg = 0; reg < 4; ++reg) {
        int row = rbase + reg;
        float v[6];
#pragma unroll
        for (int nn = 0; nn < 6; ++nn) {
            v[nn] = acc[nn][reg];
            if (EPI >= 1) v[nn] += bcol[nn];
            if (EPI == 1) v[nn] = fmaxf(v[nn], 0.f);
            if (EPI == 4) v[nn] = gelu_f(v[nn]);
        }
        if (EPI == 2 || EPI == 4) {
            float s = 0.f, s2 = 0.f;
#pragma unroll
            for (int nn = 0; nn < 6; ++nn) { s += v[nn]; s2 += v[nn] * v[nn]; }
#pragma unroll
            for (int off = 1; off < 16; off <<= 1) { s += __shfl_xor(s, off); s2 += __shfl_xor(s2, off); }
            float mean = s * (1.f / 96.f);
            float var = s2 * (1.f / 96.f) - mean * mean;
            float rs = rsqrtf(var + LN_EPS_F);
#pragma unroll
            for (int nn = 0; nn < 6; ++nn) v[nn] = (v[nn] - mean) * rs * gcol[nn] + ncol[nn];
        }
        if (row < N_NODES) {
#pragma unroll
            for (int nn = 0; nn < 6; ++nn) {
                size_t idx = (size_t)row * 96 + nn * 16 + lrow;
                if (EPI == 0 || EPI == 1) ((ushort*)outv)[idx] = f2bf(v[nn]);
                else if (EPI == 3) ((float*)outv)[idx] += v[nn];
                else ((float*)outv)[idx] = v[nn];
            }
        }
    }
}

// ---------- PE stage 1 ----------

__launch_bounds__(256)
__global__ void k_pe1(const float* __restrict__ eigvecs, const float* __restrict__ eigvals,
                      const float* __restrict__ pe_eps, const float* __restrict__ phi_w1,
                      ushort* __restrict__ sout) {
    const int lane = threadIdx.x & 63, wid = threadIdx.x >> 6;
    const int j2 = 64 + (lane & 31);
    float w10 = phi_w1[lane], w11 = phi_w1[96 + lane];
    float w20 = phi_w1[j2],   w21 = phi_w1[96 + j2];
    int w = blockIdx.x * 4 + wid, stride = gridDim.x * 4;
    for (int row = w; row < N_NODES; row += stride) {
        float s1 = 0.f, s2 = 0.f;
#pragma unroll
        for (int k = 0; k < K_EIG; ++k) {
            float a = eigvecs[(size_t)row * K_EIG + k];
            float b = eigvals[(size_t)row * K_EIG + k] + pe_eps[k];
            s1 += fmaxf(fmaf(a, w10, b * w11), 0.f);
            s2 += fmaxf(fmaf(a, w20, b * w21), 0.f);
        }
        sout[(size_t)row * 96 + lane] = f2bf(s1);
        if (lane < 32) sout[(size_t)row * 96 + j2] = f2bf(s2);
    }
}

// ---------- GCN aggregation: 4 edge-groups x 16 feature-lanes ----------

__launch_bounds__(256)
__global__ void k_agg(const unsigned int* __restrict__ xw, const int* __restrict__ rowst,
                      const int2* __restrict__ csr, const float* __restrict__ dinv,
                      const float* __restrict__ bias, const float* __restrict__ g,
                      const float* __restrict__ beta, float* __restrict__ h) {
    const int lane = threadIdx.x & 63, wid = threadIdx.x >> 6;
    const int f = lane & 15;    // feature lane: dwords f*3..f*3+2 = features f*6..f*6+5
    const int eg = lane >> 4;   // edge subgroup 0..3
    float bb[6], gg[6], be[6];
#pragma unroll
    for (int j = 0; j < 6; ++j) { bb[j] = bias[f * 6 + j]; gg[j] = g[f * 6 + j]; be[j] = beta[f * 6 + j]; }
    int w = blockIdx.x * 4 + wid, stride = gridDim.x * 4;
    for (int row = w; row < N_NODES; row += stride) {
        int rs = rowst[row], re = rowst[row + 1];
        float dv = dinv[row], d2 = dv * dv;
        float a[6];
        if (eg == 0) {
            uint3 v = *(const uint3*)(&xw[row * 48 + f * 3]);
            a[0] = bflo(v.x) * d2; a[1] = bfhi(v.x) * d2;
            a[2] = bflo(v.y) * d2; a[3] = bfhi(v.y) * d2;
            a[4] = bflo(v.z) * d2; a[5] = bfhi(v.z) * d2;
        } else {
#pragma unroll
            for (int j = 0; j < 6; ++j) a[j] = 0.f;
        }
        int i = rs + eg;
        for (; i + 4 < re; i += 8) {
            int2 e0 = csr[i], e1 = csr[i + 4];
            uint3 v0 = *(const uint3*)(&xw[e0.x * 48 + f * 3]);
            uint3 v1 = *(const uint3*)(&xw[e1.x * 48 + f * 3]);
            float w0 = __int_as_float(e0.y), w1 = __int_as_float(e1.y);
            a[0] = fmaf(w0, bflo(v0.x), a[0]); a[1] = fmaf(w0, bfhi(v0.x), a[1]);
            a[2] = fmaf(w0, bflo(v0.y), a[2]); a[3] = fmaf(w0, bfhi(v0.y), a[3]);
            a[4] = fmaf(w0, bflo(v0.z), a[4]); a[5] = fmaf(w0, bfhi(v0.z), a[5]);
            a[0] = fmaf(w1, bflo(v1.x), a[0]); a[1] = fmaf(w1, bfhi(v1.x), a[1]);
            a[2] = fmaf(w1, bflo(v1.y), a[2]); a[3] = fmaf(w1, bfhi(v1.y), a[3]);
            a[4] = fmaf(w1, bflo(v1.z), a[4]); a[5] = fmaf(w1, bfhi(v1.z), a[5]);
        }
        if (i < re) {
            int2 e0 = csr[i];
            uint3 v0 = *(const uint3*)(&xw[e0.x * 48 + f * 3]);
            float w0 = __int_as_float(e0.y);
            a[0] = fmaf(w0, bflo(v0.x), a[0]); a[1] = fmaf(w0, bfhi(v0.x), a[1]);
            a[2] = fmaf(w0, bflo(v0.y), a[2]); a[3] = fmaf(w0, bfhi(v0.y), a[3]);
            a[4] = fmaf(w0, bflo(v0.z), a[4]); a[5] = fmaf(w0, bfhi(v0.z), a[5]);
        }
#pragma unroll
        for (int j = 0; j < 6; ++j) {
            a[j] += __shfl_xor(a[j], 16);
            a[j] += __shfl_xor(a[j], 32);
        }
        float s = 0.f, s2 = 0.f;
#pragma unroll
        for (int j = 0; j < 6; ++j) {
            a[j] += bb[j];
            a[j] = gelu_f(a[j]);
            s += a[j]; s2 += a[j] * a[j];
        }
#pragma unroll
        for (int off = 1; off < 16; off <<= 1) { s += __shfl_xor(s, off); s2 += __shfl_xor(s2, off); }
        float mean = s * (1.f / 96.f);
        float var = s2 * (1.f / 96.f) - mean * mean;
        float rs_ = rsqrtf(var + LN_EPS_F);
        if (lane < 16) {
            float2* hp = (float2*)(h + (size_t)row * 96 + f * 6);
            float2 h0 = hp[0], h1 = hp[1], h2 = hp[2];
            h0.x += (a[0] - mean) * rs_ * gg[0] + be[0];
            h0.y += (a[1] - mean) * rs_ * gg[1] + be[1];
            h1.x += (a[2] - mean) * rs_ * gg[2] + be[2];
            h1.y += (a[3] - mean) * rs_ * gg[3] + be[3];
            h2.x += (a[4] - mean) * rs_ * gg[4] + be[4];
            h2.y += (a[5] - mean) * rs_ * gg[5] + be[5];
            hp[0] = h0; hp[1] = h1; hp[2] = h2;
        }
    }
}

// ---------- head stage 2: out = Z @ head_w2 + head_b2 ----------

__launch_bounds__(256)
__global__ void k_headb(const float* __restrict__ Z, const float* __restrict__ W2,
                        const float* __restrict__ b2, float* __restrict__ out) {
    __shared__ float Wl[96 * C_DIM];
    for (int i = threadIdx.x; i < 96 * C_DIM; i += 256) Wl[i] = W2[i];
    __syncthreads();
    const int lane = threadIdx.x & 63, wid = threadIdx.x >> 6;
    float b2r[C_DIM];
#pragma unroll
    for (int j = 0; j < C_DIM; ++j) b2r[j] = b2[j];
    int w = blockIdx.x * 4 + wid, stride = gridDim.x * 4;
    for (int row = w; row < N_NODES; row += stride) {
        const float* zr = Z + (size_t)row * 96;
        float z0 = zr[lane];
        float z1 = (lane < 32) ? zr[64 + lane] : 0.f;
        float acc[C_DIM];
#pragma unroll
        for (int j = 0; j < C_DIM; ++j) {
            acc[j] = z0 * Wl[lane * C_DIM + j];
            if (lane < 32) acc[j] = fmaf(z1, Wl[(64 + lane) * C_DIM + j], acc[j]);
        }
#pragma unroll
        for (int j = 0; j < C_DIM; ++j) acc[j] = wave_sum64(acc[j]);
        if (lane == 0) {
#pragma unroll
            for (int j = 0; j < C_DIM; ++j) out[(size_t)row * C_DIM + j] = acc[j] + b2r[j];
        }
    }
}

// ---------- host ----------

extern "C" void kernel_launch(void* const* d_in, const int* in_sizes, int n_in,
                              void* d_out, int out_size, void* d_ws, size_t ws_size,
                              hipStream_t stream) {
    (void)in_sizes; (void)n_in; (void)out_size; (void)ws_size;
    const float* x       = (const float*)d_in[0];
    const int*   eidx    = (const int*)d_in[1];
    const float* eigvecs = (const float*)d_in[2];
    const float* eigvals = (const float*)d_in[3];
    const float* enc_W   = (const float*)d_in[4];
    const float* enc_b   = (const float*)d_in[5];
    const float* in_g    = (const float*)d_in[6];
    const float* in_b    = (const float*)d_in[7];
    const float* phi_w1  = (const float*)d_in[8];
    const float* phi_w2  = (const float*)d_in[9];
    const float* rho_w1  = (const float*)d_in[10];
    const float* rho_b1  = (const float*)d_in[11];
    const float* rho_w2  = (const float*)d_in[12];
    const float* rho_b2  = (const float*)d_in[13];
    const float* pe_eps  = (const float*)d_in[14];
    const float* conv_W  = (const float*)d_in[15];
    const float* conv_b  = (const float*)d_in[16];
    const float* norm_g  = (const float*)d_in[17];
    const float* norm_b  = (const float*)d_in[18];
    const float* head_w1 = (const float*)d_in[19];
    const float* head_b1 = (const float*)d_in[20];
    const float* head_g  = (const float*)d_in[21];
    const float* head_b  = (const float*)d_in[22];
    const float* head_w2 = (const float*)d_in[23];
    const float* head_b2 = (const float*)d_in[24];
    float* out = (float*)d_out;

    const int* src = eidx;
    const int* dst = eidx + N_EDGES;

    char* ws = (char*)d_ws;
    size_t off = 0;
    auto alloc = [&](size_t bytes) {
        void* p = ws + off;
        off += (bytes + 255) & ~(size_t)255;
        return p;
    };
    float*  h     = (float*)alloc(sizeof(float) * (size_t)N_NODES * H_DIM);
    ushort* bufA  = (ushort*)alloc(sizeof(ushort) * (size_t)N_NODES * H_DIM);
    ushort* bufB  = (ushort*)alloc(sizeof(ushort) * (size_t)N_NODES * H_DIM);
    float*  zf    = (float*)bufA;  // aliases bufA+bufB after convs
    ushort* wbf   = (ushort*)alloc(sizeof(ushort) * (12288 + 8 * 9216));
    int*    cnt    = (int*)alloc(sizeof(int) * (N_NODES + 1));
    int*    cursor = (int*)alloc(sizeof(int) * N_NODES);
    int*    rowst  = (int*)alloc(sizeof(int) * (N_NODES + 1));
    float*  dinv   = (float*)alloc(sizeof(float) * N_NODES);
    int2*   csr    = (int2*)alloc(sizeof(int2) * N_EDGES);
    int*    btot   = (int*)alloc(sizeof(int) * 64);
    int*    bpre   = (int*)alloc(sizeof(int) * 64);

    hipMemsetAsync(cnt, 0, (size_t)((char*)rowst - (char*)cnt), stream);

    const int eb = (N_EDGES + 255) / 256;
    const int nb = (N_NODES + 255) / 256;
    const int gb = (N_NODES + 63) / 64;
    const int sb = (N_NODES + 1023) / 1024;  // 49

    WSrc wsrc;
    wsrc.p[0] = enc_W; wsrc.p[1] = phi_w2; wsrc.p[2] = rho_w1; wsrc.p[3] = rho_w2;
    for (int l = 0; l < 4; ++l) wsrc.p[4 + l] = conv_W + (size_t)l * 9216;
    wsrc.p[8] = head_w1;
    k_prep<<<(12288 + 8 * 9216 + 255) / 256, 256, 0, stream>>>(wsrc, wbf);

    k_count<<<eb, 256, 0, stream>>>(dst, cnt);
    k_dinv<<<nb, 256, 0, stream>>>(cnt, dinv);
    k_scanA<<<sb, 1024, 0, stream>>>(cnt, rowst, btot, N_NODES);
    k_scanB<<<1, 64, 0, stream>>>(btot, bpre, rowst, N_NODES, sb);
    k_scanC<<<sb, 1024, 0, stream>>>(rowst, bpre, N_NODES);
    k_fill<<<eb, 256, 0, stream>>>(src, dst, dinv, rowst, cursor, csr);

    const ushort* w_enc  = wbf;
    const ushort* w_phi2 = wbf + 12288;
    const ushort* w_rho1 = wbf + 12288 + 9216;
    const ushort* w_rho2 = wbf + 12288 + 2 * 9216;
    const ushort* w_head = wbf + 12288 + 7 * 9216;

    // encoder
    k_gemm<IN_DIM, float, 2><<<gb, 256, 0, stream>>>(x, w_enc, enc_b, in_g, in_b, h);

    // PE chain
    k_pe1<<<512, 256, 0, stream>>>(eigvecs, eigvals, pe_eps, phi_w1, bufA);
    k_gemm<96, ushort, 0><<<gb, 256, 0, stream>>>(bufA, w_phi2, nullptr, nullptr, nullptr, bufB);
    k_gemm<96, ushort, 1><<<gb, 256, 0, stream>>>(bufB, w_rho1, rho_b1, nullptr, nullptr, bufA);
    k_gemm<96, ushort, 3><<<gb, 256, 0, stream>>>(bufA, w_rho2, rho_b2, nullptr, nullptr, h);

    // GCN layers
    for (int l = 0; l < L_LAYERS; ++l) {
        k_gemm<96, float, 0><<<gb, 256, 0, stream>>>(h, wbf + 12288 + (size_t)(3 + l) * 9216,
                                                     nullptr, nullptr, nullptr, bufA);
        k_agg<<<2048, 256, 0, stream>>>((const unsigned int*)bufA, rowst, csr, dinv,
                                        conv_b + (size_t)l * 96, norm_g + (size_t)l * 96,
                                        norm_b + (size_t)l * 96, h);
    }

    // head
    k_gemm<96, float, 4><<<gb, 256, 0, stream>>>(h, w_head, head_b1, head_g, head_b, zf);
    k_headb<<<512, 256, 0, stream>>>(zf, head_w2, head_b2, out);
}

// Round 4
// 340.632 us; speedup vs baseline: 4.7380x; 1.1243x over previous
//
#include <hip/hip_runtime.h>
#include <hip/hip_bf16.h>

#define N_NODES 50000
#define N_EDGES 800000
#define IN_DIM  128
#define H_DIM   96
#define C_DIM   10
#define L_LAYERS 4
#define K_EIG   16
#define LN_EPS_F 1e-5f

typedef __attribute__((ext_vector_type(8))) short bf16x8;
typedef __attribute__((ext_vector_type(4))) float f32x4;

// ---------- device helpers ----------

__device__ __forceinline__ float gelu_f(float x) {
    return 0.5f * x * (1.0f + erff(x * 0.7071067811865476f));
}

__device__ __forceinline__ ushort f2bf(float f) {
    union { float f; unsigned int u; } v; v.f = f;
    unsigned int r = v.u + 0x7fffu + ((v.u >> 16) & 1u);
    return (ushort)(r >> 16);
}

__device__ __forceinline__ float bflo(unsigned int v) { return __uint_as_float(v << 16); }
__device__ __forceinline__ float bfhi(unsigned int v) { return __uint_as_float(v & 0xffff0000u); }

// ---------- graph preprocessing ----------

__global__ void k_count(const int* __restrict__ dst, int* __restrict__ cnt) {
    int e = blockIdx.x * 256 + threadIdx.x;
    if (e < N_EDGES) atomicAdd(&cnt[dst[e]], 1);
}

// phase A of scan (+ fused dinv)
__global__ void k_scanA(const int* __restrict__ cnt, int* __restrict__ rowst,
                        int* __restrict__ btot, float* __restrict__ dinv, int n) {
    __shared__ int wsum[16];
    const int tid = threadIdx.x, lane = tid & 63, wid = tid >> 6;
    int i = blockIdx.x * 1024 + tid;
    int v = (i < n) ? cnt[i] : 0;
    if (i < n) dinv[i] = rsqrtf((float)v + 1.0f);
    int s = v;
#pragma unroll
    for (int off = 1; off < 64; off <<= 1) {
        int t = __shfl_up(s, off);
        if (lane >= off) s += t;
    }
    if (lane == 63) wsum[wid] = s;
    __syncthreads();
    if (tid < 64) {
        int ws = (lane < 16) ? wsum[lane] : 0;
#pragma unroll
        for (int off = 1; off < 16; off <<= 1) {
            int t = __shfl_up(ws, off);
            if (lane >= off) ws += t;
        }
        if (lane < 16) wsum[lane] = ws;
    }
    __syncthreads();
    int woff = (wid > 0) ? wsum[wid - 1] : 0;
    if (i < n) rowst[i] = woff + s - v;
    if (tid == 0) btot[blockIdx.x] = wsum[15];
}

__global__ void k_scanB(int* __restrict__ btot, int* __restrict__ bpre,
                        int* __restrict__ rowst, int n, int nblk) {
    int lane = threadIdx.x;
    int v = (lane < nblk) ? btot[lane] : 0;
    int s = v;
#pragma unroll
    for (int off = 1; off < 64; off <<= 1) {
        int t = __shfl_up(s, off);
        if (lane >= off) s += t;
    }
    if (lane < nblk) bpre[lane] = s - v;
    if (lane == 63) rowst[n] = s;
}

__global__ void k_scanC(int* __restrict__ rowst, const int* __restrict__ bpre, int n) {
    int i = blockIdx.x * 1024 + threadIdx.x;
    if (i < n) rowst[i] += bpre[blockIdx.x];
}

__global__ void k_fill(const int* __restrict__ src, const int* __restrict__ dst,
                       const float* __restrict__ dinv, const int* __restrict__ rowst,
                       int* __restrict__ cursor, int2* __restrict__ csr) {
    int e = blockIdx.x * 256 + threadIdx.x;
    if (e >= N_EDGES) return;
    int s = src[e], d = dst[e];
    int p = atomicAdd(&cursor[d], 1);
    csr[rowst[d] + p] = make_int2(s, __float_as_int(dinv[s] * dinv[d]));
}

// ---------- weight prep: transpose + bf16 ----------
// layout: [0,12288): enc_W ([n][k], K=128); then 8 mats of 9216 (K=96):
// phi_w2, rho_w1, rho_w2, conv0..3, head_w1

struct WSrc { const float* p[9]; };

__global__ void k_prep(WSrc ws, ushort* __restrict__ out) {
    int idx = blockIdx.x * 256 + threadIdx.x;
    if (idx < 12288) {
        int n = idx >> 7, k = idx & 127;
        out[idx] = f2bf(ws.p[0][k * 96 + n]);
    } else if (idx < 12288 + 8 * 9216) {
        int j = idx - 12288;
        int m = j / 9216, r = j - m * 9216;
        int n = r / 96, k = r - n * 96;
        out[idx] = f2bf(ws.p[m + 1][k * 96 + n]);
    }
}

// ---------- MFMA GEMM, 128-row tiles: out[M,96] = epi(X[M,K] @ W[K,96]) ----------
// EPI 0: -> bf16 out
// EPI 2: LN(.+bias; g,beta) -> f32
// EPI 5: head: t = LN(gelu(.+bias); g,beta); out = t @ W2 + b2  (96 -> 10, f32)

template <int K_DIM, typename XT, int EPI>
__launch_bounds__(256)
__global__ void k_gemm(const XT* __restrict__ X, const ushort* __restrict__ Wt,
                       const float* __restrict__ bias, const float* __restrict__ g,
                       const float* __restrict__ beta,
                       const float* __restrict__ W2, const float* __restrict__ b2,
                       void* __restrict__ outv) {
    constexpr int KP = K_DIM + 8;
    __shared__ ushort Xl[128 * KP];
    __shared__ ushort Wl[96 * KP];
    __shared__ float W2l[(EPI == 5) ? 96 * 11 : 4];
    const int t = threadIdx.x;
    const int base = blockIdx.x * 128;

    for (int i = t; i < 96 * (K_DIM / 8); i += 256) {
        int n = i / (K_DIM / 8), kc = (i - n * (K_DIM / 8)) * 8;
        *(uint4*)(&Wl[n * KP + kc]) = *(const uint4*)(&Wt[n * K_DIM + kc]);
    }
    constexpr int CH = 128 * K_DIM / 8;
    for (int i = t; i < CH; i += 256) {
        int r = (i * 8) / K_DIM, k = (i * 8) - r * K_DIM;
        int row = base + r;
        uint4 pk;
        if (row < N_NODES) {
            if constexpr (sizeof(XT) == 4) {
                const float4* p = (const float4*)((const float*)X + (size_t)row * K_DIM + k);
                float4 a = p[0], b = p[1];
                pk.x = (unsigned)f2bf(a.x) | ((unsigned)f2bf(a.y) << 16);
                pk.y = (unsigned)f2bf(a.z) | ((unsigned)f2bf(a.w) << 16);
                pk.z = (unsigned)f2bf(b.x) | ((unsigned)f2bf(b.y) << 16);
                pk.w = (unsigned)f2bf(b.z) | ((unsigned)f2bf(b.w) << 16);
            } else {
                pk = *(const uint4*)((const ushort*)X + (size_t)row * K_DIM + k);
            }
        } else { pk.x = 0u; pk.y = 0u; pk.z = 0u; pk.w = 0u; }
        *(uint4*)(&Xl[r * KP + k]) = pk;
    }
    if constexpr (EPI == 5) {
        for (int i = t; i < 960; i += 256) { int n = i / 10, c = i - n * 10; W2l[n * 11 + c] = W2[i]; }
    }
    __syncthreads();

    const int lane = t & 63, w = t >> 6;
    const int lrow = lane & 15, lk = (lane >> 4) * 8;

    bf16x8 af[2][K_DIM / 32];
#pragma unroll
    for (int m = 0; m < 2; ++m)
#pragma unroll
        for (int kk = 0; kk < K_DIM / 32; ++kk)
            af[m][kk] = *(const bf16x8*)(&Xl[(w * 32 + m * 16 + lrow) * KP + kk * 32 + lk]);

    f32x4 acc[2][6];
#pragma unroll
    for (int m = 0; m < 2; ++m)
#pragma unroll
        for (int nn = 0; nn < 6; ++nn) { acc[m][nn][0] = 0.f; acc[m][nn][1] = 0.f; acc[m][nn][2] = 0.f; acc[m][nn][3] = 0.f; }
#pragma unroll
    for (int nn = 0; nn < 6; ++nn) {
#pragma unroll
        for (int kk = 0; kk < K_DIM / 32; ++kk) {
            bf16x8 bf = *(const bf16x8*)(&Wl[(nn * 16 + lrow) * KP + kk * 32 + lk]);
#pragma unroll
            for (int m = 0; m < 2; ++m)
                acc[m][nn] = __builtin_amdgcn_mfma_f32_16x16x32_bf16(af[m][kk], bf, acc[m][nn], 0, 0, 0);
        }
    }

    float bcol[6], gcol[6], ncol[6];
    if (EPI == 2 || EPI == 5) {
#pragma unroll
        for (int nn = 0; nn < 6; ++nn) {
            bcol[nn] = bias[nn * 16 + lrow];
            gcol[nn] = g[nn * 16 + lrow];
            ncol[nn] = beta[nn * 16 + lrow];
        }
    }

#pragma unroll
    for (int m = 0; m < 2; ++m) {
        const int rbase = base + w * 32 + m * 16 + (lane >> 4) * 4;
#pragma unroll
        for (int reg = 0; reg < 4; ++reg) {
            int row = rbase + reg;
            float v[6];
#pragma unroll
            for (int nn = 0; nn < 6; ++nn) {
                v[nn] = acc[m][nn][reg];
                if (EPI == 2 || EPI == 5) v[nn] += bcol[nn];
                if (EPI == 5) v[nn] = gelu_f(v[nn]);
            }
            if (EPI == 2 || EPI == 5) {
                float s = 0.f, s2 = 0.f;
#pragma unroll
                for (int nn = 0; nn < 6; ++nn) { s += v[nn]; s2 += v[nn] * v[nn]; }
#pragma unroll
                for (int off = 1; off < 16; off <<= 1) { s += __shfl_xor(s, off); s2 += __shfl_xor(s2, off); }
                float mean = s * (1.f / 96.f);
                float var = s2 * (1.f / 96.f) - mean * mean;
                float rs = rsqrtf(var + LN_EPS_F);
#pragma unroll
                for (int nn = 0; nn < 6; ++nn) v[nn] = (v[nn] - mean) * rs * gcol[nn] + ncol[nn];
            }
            if constexpr (EPI == 5) {
                float pc[C_DIM];
#pragma unroll
                for (int c = 0; c < C_DIM; ++c) pc[c] = 0.f;
#pragma unroll
                for (int nn = 0; nn < 6; ++nn) {
                    const float* wr = &W2l[(nn * 16 + lrow) * 11];
#pragma unroll
                    for (int c = 0; c < C_DIM; ++c) pc[c] = fmaf(v[nn], wr[c], pc[c]);
                }
#pragma unroll
                for (int off = 1; off < 16; off <<= 1) {
#pragma unroll
                    for (int c = 0; c < C_DIM; ++c) pc[c] += __shfl_xor(pc[c], off);
                }
                if (lrow == 0 && row < N_NODES) {
#pragma unroll
                    for (int c = 0; c < C_DIM; ++c)
                        ((float*)outv)[(size_t)row * C_DIM + c] = pc[c] + b2[c];
                }
            } else if (row < N_NODES) {
#pragma unroll
                for (int nn = 0; nn < 6; ++nn) {
                    size_t idx = (size_t)row * 96 + nn * 16 + lrow;
                    if (EPI == 0) ((ushort*)outv)[idx] = f2bf(v[nn]);
                    else ((float*)outv)[idx] = v[nn];
                }
            }
        }
    }
}

// ---------- fused PE: h += rho2(relu(rho1(phi2(sum_k relu(z@phi_w1))))) ----------
// one 64-row tile per block; 3 chained MFMA stages through LDS tile T;
// single W LDS buffer re-staged between stages.

__launch_bounds__(256)
__global__ void k_pe(const float* __restrict__ eigvecs, const float* __restrict__ eigvals,
                     const float* __restrict__ pe_eps, const float* __restrict__ phi_w1,
                     const ushort* __restrict__ w_phi2, const ushort* __restrict__ w_rho1,
                     const ushort* __restrict__ w_rho2, const float* __restrict__ rho_b1,
                     const float* __restrict__ rho_b2, float* __restrict__ h,
                     ushort* __restrict__ hb) {
    constexpr int KP = 104;
    __shared__ ushort WL[96 * KP];
    __shared__ ushort T[64 * KP];
    const int t = threadIdx.x;
    const int base = blockIdx.x * 64;

    // stage phi_w2
    for (int i = t; i < 96 * 12; i += 256) {
        int n = i / 12, kc = (i - n * 12) * 8;
        *(uint4*)(&WL[n * KP + kc]) = *(const uint4*)(&w_phi2[n * 96 + kc]);
    }
    // pe stage-1 per-thread: 4 threads/row, 24 features each
    {
        int r = t >> 2, jg = t & 3;
        int row = base + r;
        float s[24];
#pragma unroll
        for (int j = 0; j < 24; ++j) s[j] = 0.f;
        if (row < N_NODES) {
            float w0[24], w1v[24];
#pragma unroll
            for (int j = 0; j < 24; ++j) { w0[j] = phi_w1[jg * 24 + j]; w1v[j] = phi_w1[96 + jg * 24 + j]; }
            for (int k = 0; k < K_EIG; ++k) {
                float a = eigvecs[(size_t)row * K_EIG + k];
                float b = eigvals[(size_t)row * K_EIG + k] + pe_eps[k];
#pragma unroll
                for (int j = 0; j < 24; ++j) s[j] += fmaxf(fmaf(a, w0[j], b * w1v[j]), 0.f);
            }
        }
#pragma unroll
        for (int j = 0; j < 12; ++j) {
            unsigned pk = (unsigned)f2bf(s[2 * j]) | ((unsigned)f2bf(s[2 * j + 1]) << 16);
            *(unsigned*)(&T[r * KP + jg * 24 + 2 * j]) = pk;
        }
    }
    __syncthreads();

    const int lane = t & 63, w = t >> 6;
    const int lrow = lane & 15, lk = (lane >> 4) * 8;
    const int rsub = (lane >> 4) * 4;
    float bc2[6], bc3[6];
#pragma unroll
    for (int nn = 0; nn < 6; ++nn) { bc2[nn] = rho_b1[nn * 16 + lrow]; bc3[nn] = rho_b2[nn * 16 + lrow]; }

    f32x4 acc[6];

    // ---- stage 1: T @ phi_w2 -> T ----
    {
        bf16x8 af[3];
#pragma unroll
        for (int kk = 0; kk < 3; ++kk) af[kk] = *(const bf16x8*)(&T[(w * 16 + lrow) * KP + kk * 32 + lk]);
#pragma unroll
        for (int nn = 0; nn < 6; ++nn) { acc[nn][0] = 0.f; acc[nn][1] = 0.f; acc[nn][2] = 0.f; acc[nn][3] = 0.f; }
#pragma unroll
        for (int nn = 0; nn < 6; ++nn)
#pragma unroll
            for (int kk = 0; kk < 3; ++kk)
                acc[nn] = __builtin_amdgcn_mfma_f32_16x16x32_bf16(
                    af[kk], *(const bf16x8*)(&WL[(nn * 16 + lrow) * KP + kk * 32 + lk]), acc[nn], 0, 0, 0);
        __syncthreads();  // all T/WL reads done
#pragma unroll
        for (int reg = 0; reg < 4; ++reg)
#pragma unroll
            for (int nn = 0; nn < 6; ++nn)
                T[(w * 16 + rsub + reg) * KP + nn * 16 + lrow] = f2bf(acc[nn][reg]);
        for (int i = t; i < 96 * 12; i += 256) {
            int n = i / 12, kc = (i - n * 12) * 8;
            *(uint4*)(&WL[n * KP + kc]) = *(const uint4*)(&w_rho1[n * 96 + kc]);
        }
        __syncthreads();
    }

    // ---- stage 2: relu(T @ rho_w1 + b1) -> T ----
    {
        bf16x8 af[3];
#pragma unroll
        for (int kk = 0; kk < 3; ++kk) af[kk] = *(const bf16x8*)(&T[(w * 16 + lrow) * KP + kk * 32 + lk]);
#pragma unroll
        for (int nn = 0; nn < 6; ++nn) { acc[nn][0] = 0.f; acc[nn][1] = 0.f; acc[nn][2] = 0.f; acc[nn][3] = 0.f; }
#pragma unroll
        for (int nn = 0; nn < 6; ++nn)
#pragma unroll
            for (int kk = 0; kk < 3; ++kk)
                acc[nn] = __builtin_amdgcn_mfma_f32_16x16x32_bf16(
                    af[kk], *(const bf16x8*)(&WL[(nn * 16 + lrow) * KP + kk * 32 + lk]), acc[nn], 0, 0, 0);
        __syncthreads();
#pragma unroll
        for (int reg = 0; reg < 4; ++reg)
#pragma unroll
            for (int nn = 0; nn < 6; ++nn)
                T[(w * 16 + rsub + reg) * KP + nn * 16 + lrow] = f2bf(fmaxf(acc[nn][reg] + bc2[nn], 0.f));
        for (int i = t; i < 96 * 12; i += 256) {
            int n = i / 12, kc = (i - n * 12) * 8;
            *(uint4*)(&WL[n * KP + kc]) = *(const uint4*)(&w_rho2[n * 96 + kc]);
        }
        __syncthreads();
    }

    // ---- stage 3: h += T @ rho_w2 + b2 ; hb = bf16(h) ----
    {
        bf16x8 af[3];
#pragma unroll
        for (int kk = 0; kk < 3; ++kk) af[kk] = *(const bf16x8*)(&T[(w * 16 + lrow) * KP + kk * 32 + lk]);
#pragma unroll
        for (int nn = 0; nn < 6; ++nn) { acc[nn][0] = 0.f; acc[nn][1] = 0.f; acc[nn][2] = 0.f; acc[nn][3] = 0.f; }
#pragma unroll
        for (int nn = 0; nn < 6; ++nn)
#pragma unroll
            for (int kk = 0; kk < 3; ++kk)
                acc[nn] = __builtin_amdgcn_mfma_f32_16x16x32_bf16(
                    af[kk], *(const bf16x8*)(&WL[(nn * 16 + lrow) * KP + kk * 32 + lk]), acc[nn], 0, 0, 0);
#pragma unroll
        for (int reg = 0; reg < 4; ++reg) {
            int row = base + w * 16 + rsub + reg;
            if (row < N_NODES) {
#pragma unroll
                for (int nn = 0; nn < 6; ++nn) {
                    size_t idx = (size_t)row * 96 + nn * 16 + lrow;
                    float hv = h[idx] + acc[nn][reg] + bc3[nn];
                    h[idx] = hv;
                    hb[idx] = f2bf(hv);
                }
            }
        }
    }
}

// ---------- GCN aggregation: 4 edge-groups x 16 feature-lanes ----------

__launch_bounds__(256)
__global__ void k_agg(const unsigned int* __restrict__ xw, const int* __restrict__ rowst,
                      const int2* __restrict__ csr, const float* __restrict__ dinv,
                      const float* __restrict__ bias, const float* __restrict__ g,
                      const float* __restrict__ beta, float* __restrict__ h,
                      ushort* __restrict__ hb) {
    const int lane = threadIdx.x & 63, wid = threadIdx.x >> 6;
    const int f = lane & 15;
    const int eg = lane >> 4;
    float bb[6], gg[6], be[6];
#pragma unroll
    for (int j = 0; j < 6; ++j) { bb[j] = bias[f * 6 + j]; gg[j] = g[f * 6 + j]; be[j] = beta[f * 6 + j]; }
    int w = blockIdx.x * 4 + wid, stride = gridDim.x * 4;
    for (int row = w; row < N_NODES; row += stride) {
        int rs = rowst[row], re = rowst[row + 1];
        float dv = dinv[row], d2 = dv * dv;
        float a[6];
        if (eg == 0) {
            uint3 v = *(const uint3*)(&xw[row * 48 + f * 3]);
            a[0] = bflo(v.x) * d2; a[1] = bfhi(v.x) * d2;
            a[2] = bflo(v.y) * d2; a[3] = bfhi(v.y) * d2;
            a[4] = bflo(v.z) * d2; a[5] = bfhi(v.z) * d2;
        } else {
#pragma unroll
            for (int j = 0; j < 6; ++j) a[j] = 0.f;
        }
        int i = rs + eg;
        for (; i + 4 < re; i += 8) {
            int2 e0 = csr[i], e1 = csr[i + 4];
            uint3 v0 = *(const uint3*)(&xw[e0.x * 48 + f * 3]);
            uint3 v1 = *(const uint3*)(&xw[e1.x * 48 + f * 3]);
            float w0 = __int_as_float(e0.y), w1 = __int_as_float(e1.y);
            a[0] = fmaf(w0, bflo(v0.x), a[0]); a[1] = fmaf(w0, bfhi(v0.x), a[1]);
            a[2] = fmaf(w0, bflo(v0.y), a[2]); a[3] = fmaf(w0, bfhi(v0.y), a[3]);
            a[4] = fmaf(w0, bflo(v0.z), a[4]); a[5] = fmaf(w0, bfhi(v0.z), a[5]);
            a[0] = fmaf(w1, bflo(v1.x), a[0]); a[1] = fmaf(w1, bfhi(v1.x), a[1]);
            a[2] = fmaf(w1, bflo(v1.y), a[2]); a[3] = fmaf(w1, bfhi(v1.y), a[3]);
            a[4] = fmaf(w1, bflo(v1.z), a[4]); a[5] = fmaf(w1, bfhi(v1.z), a[5]);
        }
        if (i < re) {
            int2 e0 = csr[i];
            uint3 v0 = *(const uint3*)(&xw[e0.x * 48 + f * 3]);
            float w0 = __int_as_float(e0.y);
            a[0] = fmaf(w0, bflo(v0.x), a[0]); a[1] = fmaf(w0, bfhi(v0.x), a[1]);
            a[2] = fmaf(w0, bflo(v0.y), a[2]); a[3] = fmaf(w0, bfhi(v0.y), a[3]);
            a[4] = fmaf(w0, bflo(v0.z), a[4]); a[5] = fmaf(w0, bfhi(v0.z), a[5]);
        }
#pragma unroll
        for (int j = 0; j < 6; ++j) {
            a[j] += __shfl_xor(a[j], 16);
            a[j] += __shfl_xor(a[j], 32);
        }
        float s = 0.f, s2 = 0.f;
#pragma unroll
        for (int j = 0; j < 6; ++j) {
            a[j] += bb[j];
            a[j] = gelu_f(a[j]);
            s += a[j]; s2 += a[j] * a[j];
        }
#pragma unroll
        for (int off = 1; off < 16; off <<= 1) { s += __shfl_xor(s, off); s2 += __shfl_xor(s2, off); }
        float mean = s * (1.f / 96.f);
        float var = s2 * (1.f / 96.f) - mean * mean;
        float rs_ = rsqrtf(var + LN_EPS_F);
        if (lane < 16) {
            float2* hp = (float2*)(h + (size_t)row * 96 + f * 6);
            float2 h0 = hp[0], h1 = hp[1], h2 = hp[2];
            float v0 = h0.x + (a[0] - mean) * rs_ * gg[0] + be[0];
            float v1 = h0.y + (a[1] - mean) * rs_ * gg[1] + be[1];
            float v2 = h1.x + (a[2] - mean) * rs_ * gg[2] + be[2];
            float v3 = h1.y + (a[3] - mean) * rs_ * gg[3] + be[3];
            float v4 = h2.x + (a[4] - mean) * rs_ * gg[4] + be[4];
            float v5 = h2.y + (a[5] - mean) * rs_ * gg[5] + be[5];
            hp[0] = make_float2(v0, v1); hp[1] = make_float2(v2, v3); hp[2] = make_float2(v4, v5);
            unsigned int* hbp = (unsigned int*)(hb + (size_t)row * 96 + f * 6);
            hbp[0] = (unsigned)f2bf(v0) | ((unsigned)f2bf(v1) << 16);
            hbp[1] = (unsigned)f2bf(v2) | ((unsigned)f2bf(v3) << 16);
            hbp[2] = (unsigned)f2bf(v4) | ((unsigned)f2bf(v5) << 16);
        }
    }
}

// ---------- host ----------

extern "C" void kernel_launch(void* const* d_in, const int* in_sizes, int n_in,
                              void* d_out, int out_size, void* d_ws, size_t ws_size,
                              hipStream_t stream) {
    (void)in_sizes; (void)n_in; (void)out_size; (void)ws_size;
    const float* x       = (const float*)d_in[0];
    const int*   eidx    = (const int*)d_in[1];
    const float* eigvecs = (const float*)d_in[2];
    const float* eigvals = (const float*)d_in[3];
    const float* enc_W   = (const float*)d_in[4];
    const float* enc_b   = (const float*)d_in[5];
    const float* in_g    = (const float*)d_in[6];
    const float* in_b    = (const float*)d_in[7];
    const float* phi_w1  = (const float*)d_in[8];
    const float* phi_w2  = (const float*)d_in[9];
    const float* rho_w1  = (const float*)d_in[10];
    const float* rho_b1  = (const float*)d_in[11];
    const float* rho_w2  = (const float*)d_in[12];
    const float* rho_b2  = (const float*)d_in[13];
    const float* pe_eps  = (const float*)d_in[14];
    const float* conv_W  = (const float*)d_in[15];
    const float* conv_b  = (const float*)d_in[16];
    const float* norm_g  = (const float*)d_in[17];
    const float* norm_b  = (const float*)d_in[18];
    const float* head_w1 = (const float*)d_in[19];
    const float* head_b1 = (const float*)d_in[20];
    const float* head_g  = (const float*)d_in[21];
    const float* head_b  = (const float*)d_in[22];
    const float* head_w2 = (const float*)d_in[23];
    const float* head_b2 = (const float*)d_in[24];
    float* out = (float*)d_out;

    const int* src = eidx;
    const int* dst = eidx + N_EDGES;

    char* ws = (char*)d_ws;
    size_t off = 0;
    auto alloc = [&](size_t bytes) {
        void* p = ws + off;
        off += (bytes + 255) & ~(size_t)255;
        return p;
    };
    float*  h      = (float*)alloc(sizeof(float) * (size_t)N_NODES * H_DIM);
    ushort* hb     = (ushort*)alloc(sizeof(ushort) * (size_t)N_NODES * H_DIM);
    ushort* bufA   = (ushort*)alloc(sizeof(ushort) * (size_t)N_NODES * H_DIM);
    ushort* wbf    = (ushort*)alloc(sizeof(ushort) * (12288 + 8 * 9216));
    int*    cnt    = (int*)alloc(sizeof(int) * (N_NODES + 1));
    int*    cursor = (int*)alloc(sizeof(int) * N_NODES);
    int*    rowst  = (int*)alloc(sizeof(int) * (N_NODES + 1));
    float*  dinv   = (float*)alloc(sizeof(float) * N_NODES);
    int2*   csr    = (int2*)alloc(sizeof(int2) * N_EDGES);
    int*    btot   = (int*)alloc(sizeof(int) * 64);
    int*    bpre   = (int*)alloc(sizeof(int) * 64);

    hipMemsetAsync(cnt, 0, (size_t)((char*)rowst - (char*)cnt), stream);

    const int eb = (N_EDGES + 255) / 256;
    const int gb = (N_NODES + 127) / 128;          // 391
    const int pb = (N_NODES + 63) / 64;            // 782
    const int sb = (N_NODES + 1023) / 1024;        // 49

    WSrc wsrc;
    wsrc.p[0] = enc_W; wsrc.p[1] = phi_w2; wsrc.p[2] = rho_w1; wsrc.p[3] = rho_w2;
    for (int l = 0; l < 4; ++l) wsrc.p[4 + l] = conv_W + (size_t)l * 9216;
    wsrc.p[8] = head_w1;
    k_prep<<<(12288 + 8 * 9216 + 255) / 256, 256, 0, stream>>>(wsrc, wbf);

    k_count<<<eb, 256, 0, stream>>>(dst, cnt);
    k_scanA<<<sb, 1024, 0, stream>>>(cnt, rowst, btot, dinv, N_NODES);
    k_scanB<<<1, 64, 0, stream>>>(btot, bpre, rowst, N_NODES, sb);
    k_scanC<<<sb, 1024, 0, stream>>>(rowst, bpre, N_NODES);
    k_fill<<<eb, 256, 0, stream>>>(src, dst, dinv, rowst, cursor, csr);

    const ushort* w_enc  = wbf;
    const ushort* w_phi2 = wbf + 12288;
    const ushort* w_rho1 = wbf + 12288 + 9216;
    const ushort* w_rho2 = wbf + 12288 + 2 * 9216;
    const ushort* w_head = wbf + 12288 + 7 * 9216;

    // encoder: h = LN(x @ enc_W + enc_b)
    k_gemm<IN_DIM, float, 2><<<gb, 256, 0, stream>>>(x, w_enc, enc_b, in_g, in_b,
                                                     nullptr, nullptr, h);

    // fused PE chain: h += PE, hb = bf16(h)
    k_pe<<<pb, 256, 0, stream>>>(eigvecs, eigvals, pe_eps, phi_w1, w_phi2, w_rho1, w_rho2,
                                 rho_b1, rho_b2, h, hb);

    // GCN layers
    for (int l = 0; l < L_LAYERS; ++l) {
        k_gemm<96, ushort, 0><<<gb, 256, 0, stream>>>(hb, wbf + 12288 + (size_t)(3 + l) * 9216,
                                                      nullptr, nullptr, nullptr, nullptr, nullptr, bufA);
        k_agg<<<2048, 256, 0, stream>>>((const unsigned int*)bufA, rowst, csr, dinv,
                                        conv_b + (size_t)l * 96, norm_g + (size_t)l * 96,
                                        norm_b + (size_t)l * 96, h, hb);
    }

    // fused head: out = LN(gelu(h@w1+b1)) @ w2 + b2
    k_gemm<96, ushort, 5><<<gb, 256, 0, stream>>>(hb, w_head, head_b1, head_g, head_b,
                                                  head_w2, head_b2, out);
}